// Round 4
// baseline (94.931 us; speedup 1.0000x reference)
//
#include <hip/hip_runtime.h>

// Soft-sphere multi-species: energy + analytic forces. N=4096, S=8.
// Two-kernel, zero-free, atomic-free structure:
//   Kernel A: (N/TI) x NCHUNK grid; each thread = particle i vs a 64-j chunk
//             staged in LDS. Writes force partials to d_ws (SoA, coalesced)
//             and per-block energy partials. Every slot written -> no memset.
//   Kernel B: sums the 64 chunk-partials per (i,axis) -> out[1+3i+axis];
//             block 0 / wave 0 reduces 1024 energy partials -> out[0].
// Hot loop: |MIC| via min(|d|, L-|d|) (abs folds to VOP3 modifier, 3 ops/axis);
// signed MIC recomputed only in the rare in-range branch. Branch gated on
// r2 < min(sigma_max^2, CUT2) -- exact, since sigma<r<1.5 pairs contribute 0
// to both energy and gradient. f^(alpha-1) via hardware exp2/log2.

#define TI 256
#define TJ 64
#define NCHUNK 64          // N / TJ
#define CUT2 2.25f         // CUTOFF=1.5 squared

__device__ __forceinline__ float fast_pow(float f, float e) {
    // f > 0 guaranteed. 2^(e * log2(f)) on the hardware transcendental pipe.
    return __builtin_amdgcn_exp2f(e * __builtin_amdgcn_logf(f));
}

__global__ __launch_bounds__(TI) void pair_kernel(
    const float* __restrict__ pos,
    const float* __restrict__ cell,
    const float* __restrict__ sigm,
    const float* __restrict__ epsm,
    const float* __restrict__ alpm,
    const int*   __restrict__ spec,
    float* __restrict__ ws,    // [3][NCHUNK][n] force partials, then [NCHUNK*gridX] energies
    int n)
{
    __shared__ float4 sh_pos[TJ];   // j positions + species bits in .w
    __shared__ float4 sh_tab[64];   // {inv_sig, alpha-1, eps/alpha, eps/sig}
    __shared__ float  sh_red[TI / 64];
    __shared__ float  sh_thr2;

    const int tid = threadIdx.x;
    const int j0  = blockIdx.y * TJ;

    if (tid < 64) {
        // Species-pair coefficient tables (8x8 = 64 entries).
        float sg = sigm[tid], ep = epsm[tid], al = alpm[tid];
        float inv_sg = 1.0f / sg;
        sh_tab[tid] = make_float4(inv_sg, al - 1.0f, ep / al, ep * inv_sg);
        // j-chunk staging (TJ == 64).
        int j = j0 + tid;
        sh_pos[tid] = make_float4(pos[3 * j + 0], pos[3 * j + 1],
                                  pos[3 * j + 2], __int_as_float(spec[j]));
        // Wave 0: reduce max sigma^2 -> tightened branch threshold.
        float mx = sg * sg;
        for (int off = 32; off > 0; off >>= 1)
            mx = fmaxf(mx, __shfl_down(mx, off, 64));
        if (tid == 0) sh_thr2 = fminf(mx, CUT2);
    }

    // Cell (uniform -> SGPRs).
    const float m00 = cell[0], m01 = cell[1], m02 = cell[2];
    const float m10 = cell[3], m11 = cell[4], m12 = cell[5];
    const float m20 = cell[6], m21 = cell[7], m22 = cell[8];
    const bool diag = (m01 == 0.0f) & (m02 == 0.0f) & (m10 == 0.0f) &
                      (m12 == 0.0f) & (m20 == 0.0f) & (m21 == 0.0f);

    const int   i   = blockIdx.x * TI + tid;
    const float px  = pos[3 * i + 0];
    const float py  = pos[3 * i + 1];
    const float pz  = pos[3 * i + 2];
    const int   si8 = spec[i] << 3;

    __syncthreads();
    const float thr2 = sh_thr2;

    float e_acc = 0.0f, fxa = 0.0f, fya = 0.0f, fza = 0.0f;

    if (diag) {
        const float Lx = m00, Ly = m11, Lz = m22;
        const float iLx = 1.0f / Lx, iLy = 1.0f / Ly, iLz = 1.0f / Lz;
#pragma unroll 4
        for (int t = 0; t < TJ; ++t) {
            float4 pj = sh_pos[t];
            float dx = pj.x - px;
            float dy = pj.y - py;
            float dz = pj.z - pz;
            // |minimum image| per axis: min(|d|, L-|d|); abs folds to modifier.
            float ax = fabsf(dx), ay = fabsf(dy), az = fabsf(dz);
            float wx = fminf(ax, Lx - ax);
            float wy = fminf(ay, Ly - ay);
            float wz = fminf(az, Lz - az);
            float r2 = fmaf(wx, wx, fmaf(wy, wy, wz * wz));
            if (r2 < thr2 && (j0 + t) != i) {
                // Signed MIC only where needed (rare).
                float sx = fmaf(-rintf(dx * iLx), Lx, dx);
                float sy = fmaf(-rintf(dy * iLy), Ly, dy);
                float sz = fmaf(-rintf(dz * iLz), Lz, dz);
                float4 tab = sh_tab[si8 + __float_as_int(pj.w)];
                float rinv = rsqrtf(r2);
                float r    = r2 * rinv;
                float f    = fmaf(-r, tab.x, 1.0f);   // 1 - r/sig
                if (f > 0.0f) {
                    float p = fast_pow(f, tab.y);        // f^(alpha-1)
                    e_acc = fmaf(tab.z * p, f, e_acc);   // eps/alpha * f^alpha
                    float c = tab.w * p * rinv;          // eps/(sig*r)*f^(a-1)
                    fxa = fmaf(-c, sx, fxa);
                    fya = fmaf(-c, sy, fya);
                    fza = fmaf(-c, sz, fza);
                }
            }
        }
    } else {
        // General triclinic path (not taken for this input, kept for correctness).
        const float det = m00 * (m11 * m22 - m12 * m21)
                        - m01 * (m10 * m22 - m12 * m20)
                        + m02 * (m10 * m21 - m11 * m20);
        const float rdet = 1.0f / det;
        const float i00 = (m11 * m22 - m12 * m21) * rdet;
        const float i01 = (m02 * m21 - m01 * m22) * rdet;
        const float i02 = (m01 * m12 - m02 * m11) * rdet;
        const float i10 = (m12 * m20 - m10 * m22) * rdet;
        const float i11 = (m00 * m22 - m02 * m20) * rdet;
        const float i12 = (m02 * m10 - m00 * m12) * rdet;
        const float i20 = (m10 * m21 - m11 * m20) * rdet;
        const float i21 = (m01 * m20 - m00 * m21) * rdet;
        const float i22 = (m00 * m11 - m01 * m10) * rdet;
#pragma unroll 2
        for (int t = 0; t < TJ; ++t) {
            float4 pj = sh_pos[t];
            float dx = pj.x - px, dy = pj.y - py, dz = pj.z - pz;
            float fx = dx * i00 + dy * i10 + dz * i20;
            float fy = dx * i01 + dy * i11 + dz * i21;
            float fz = dx * i02 + dy * i12 + dz * i22;
            fx -= rintf(fx); fy -= rintf(fy); fz -= rintf(fz);
            float ddx = fx * m00 + fy * m10 + fz * m20;
            float ddy = fx * m01 + fy * m11 + fz * m21;
            float ddz = fx * m02 + fy * m12 + fz * m22;
            float r2 = fmaf(ddx, ddx, fmaf(ddy, ddy, ddz * ddz));
            if (r2 < thr2 && (j0 + t) != i) {
                float4 tab = sh_tab[si8 + __float_as_int(pj.w)];
                float rinv = rsqrtf(r2);
                float r    = r2 * rinv;
                float f    = fmaf(-r, tab.x, 1.0f);
                if (f > 0.0f) {
                    float p = fast_pow(f, tab.y);
                    e_acc = fmaf(tab.z * p, f, e_acc);
                    float c = tab.w * p * rinv;
                    fxa = fmaf(-c, ddx, fxa);
                    fya = fmaf(-c, ddy, fya);
                    fza = fmaf(-c, ddz, fza);
                }
            }
        }
    }

    // Force partials: SoA, coalesced plain stores (no atomics, no pre-zero).
    const int axs  = n * NCHUNK;            // per-axis stride in floats
    const int base = blockIdx.y * n + i;
    ws[0 * axs + base] = fxa;
    ws[1 * axs + base] = fya;
    ws[2 * axs + base] = fza;

    // Energy: wave shuffle reduce -> LDS across waves -> one store per block.
    for (int off = 32; off > 0; off >>= 1)
        e_acc += __shfl_down(e_acc, off, 64);
    if ((tid & 63) == 0) sh_red[tid >> 6] = e_acc;
    __syncthreads();
    if (tid == 0) {
        float tot = 0.0f;
        for (int w = 0; w < TI / 64; ++w) tot += sh_red[w];
        ws[3 * axs + blockIdx.y * gridDim.x + blockIdx.x] = tot;
    }
}

__global__ __launch_bounds__(256) void reduce_kernel(
    const float* __restrict__ ws,
    float* __restrict__ out,   // out[0]=energy, out[1..3n]=forces
    int n, int nblk_e)         // nblk_e = gridA.x * gridA.y energy partials
{
    const int gtid = blockIdx.x * 256 + threadIdx.x;   // [0, 3n)
    const int axis = gtid / n;
    const int i    = gtid - axis * n;
    const int axs  = n * NCHUNK;

    const float* p = ws + axis * axs + i;
    float s = 0.0f;
#pragma unroll
    for (int c = 0; c < NCHUNK; ++c) s += p[c * n];
    out[1 + 3 * i + axis] = s;

    // Block 0 / wave 0: reduce energy partials -> out[0].
    if (blockIdx.x == 0 && threadIdx.x < 64) {
        const float* e = ws + 3 * axs;
        float es = 0.0f;
        for (int k = threadIdx.x; k < nblk_e; k += 64) es += e[k];
        for (int off = 32; off > 0; off >>= 1)
            es += __shfl_down(es, off, 64);
        if (threadIdx.x == 0) out[0] = 0.5f * es;  // ordered pairs double-count
    }
}

extern "C" void kernel_launch(void* const* d_in, const int* in_sizes, int n_in,
                              void* d_out, int out_size, void* d_ws, size_t ws_size,
                              hipStream_t stream) {
    const float* pos  = (const float*)d_in[0];
    const float* cell = (const float*)d_in[1];
    const float* sigm = (const float*)d_in[2];
    const float* epsm = (const float*)d_in[3];
    const float* alpm = (const float*)d_in[4];
    const int*   spec = (const int*)d_in[5];
    float* out = (float*)d_out;
    float* ws  = (float*)d_ws;
    const int n = in_sizes[5];  // species array length = N (4096)

    dim3 gridA(n / TI, NCHUNK);   // TJ = n / NCHUNK
    pair_kernel<<<gridA, TI, 0, stream>>>(pos, cell, sigm, epsm, alpm,
                                          spec, ws, n);
    reduce_kernel<<<(3 * n) / 256, 256, 0, stream>>>(ws, out, n,
                                                     gridA.x * gridA.y);
}

// Round 5
// 94.425 us; speedup vs baseline: 1.0054x; 1.0054x over previous
//
#include <hip/hip_runtime.h>

// Soft-sphere multi-species: energy + analytic forces. N=4096, S=8.
// Round-3 structure (single pair kernel + small memset + atomic merge — the
// measured-fastest) with Round-4's hot-loop improvements ported in:
//   - unsigned minimum-image via min(|d|, L-|d|): 3 VALU/axis in the gate
//     (abs folds to a VOP3 input modifier); signed MIC recomputed only
//     inside the rare in-range branch.
//   - branch gated on r2 < min(sigma_max^2, CUT2): exact, since pairs with
//     sigma < r < CUTOFF contribute 0 to both energy and gradient.
//   - f^(alpha-1) via hardware v_exp_f32/v_log_f32.
// Grid: (N/TI) i-tiles x (N/TJ) j-chunks = 1024 blocks of 256 (4 waves/SIMD).

#define TI 256
#define TJ 64
#define CUT2 2.25f  // CUTOFF=1.5 squared

__device__ __forceinline__ float fast_pow(float f, float e) {
    // f > 0 guaranteed. 2^(e * log2(f)) on the hardware transcendental pipe.
    return __builtin_amdgcn_exp2f(e * __builtin_amdgcn_logf(f));
}

__global__ __launch_bounds__(TI) void soft_sphere_kernel(
    const float* __restrict__ pos,
    const float* __restrict__ cell,
    const float* __restrict__ sigm,
    const float* __restrict__ epsm,
    const float* __restrict__ alpm,
    const int*   __restrict__ spec,
    float* __restrict__ out,   // out[0]=energy, out[1..3N]=forces
    int n)
{
    __shared__ float4 sh_pos[TJ];   // j positions + species bits in .w
    __shared__ float4 sh_tab[64];   // {inv_sig, alpha-1, eps/alpha, eps/sig}
    __shared__ float  sh_red[TI / 64];
    __shared__ float  sh_thr2;

    const int tid = threadIdx.x;
    const int j0  = blockIdx.y * TJ;

    if (tid < 64) {
        // Species-pair coefficient tables (8x8 = 64 entries).
        float sg = sigm[tid], ep = epsm[tid], al = alpm[tid];
        float inv_sg = 1.0f / sg;
        sh_tab[tid] = make_float4(inv_sg, al - 1.0f, ep / al, ep * inv_sg);
        // j-chunk staging (TJ == 64).
        int j = j0 + tid;
        sh_pos[tid] = make_float4(pos[3 * j + 0], pos[3 * j + 1],
                                  pos[3 * j + 2], __int_as_float(spec[j]));
        // Wave 0: max sigma^2 -> tightened (exact) branch threshold.
        float mx = sg * sg;
        for (int off = 32; off > 0; off >>= 1)
            mx = fmaxf(mx, __shfl_down(mx, off, 64));
        if (tid == 0) sh_thr2 = fminf(mx, CUT2);
    }

    // Cell (uniform -> SGPRs).
    const float m00 = cell[0], m01 = cell[1], m02 = cell[2];
    const float m10 = cell[3], m11 = cell[4], m12 = cell[5];
    const float m20 = cell[6], m21 = cell[7], m22 = cell[8];
    const bool diag = (m01 == 0.0f) & (m02 == 0.0f) & (m10 == 0.0f) &
                      (m12 == 0.0f) & (m20 == 0.0f) & (m21 == 0.0f);

    const int   i   = blockIdx.x * TI + tid;
    const float px  = pos[3 * i + 0];
    const float py  = pos[3 * i + 1];
    const float pz  = pos[3 * i + 2];
    const int   si8 = spec[i] << 3;

    __syncthreads();
    const float thr2 = sh_thr2;

    float e_acc = 0.0f, fxa = 0.0f, fya = 0.0f, fza = 0.0f;

    if (diag) {
        const float Lx = m00, Ly = m11, Lz = m22;
        const float iLx = 1.0f / Lx, iLy = 1.0f / Ly, iLz = 1.0f / Lz;
#pragma unroll 4
        for (int t = 0; t < TJ; ++t) {
            float4 pj = sh_pos[t];
            float dx = pj.x - px;
            float dy = pj.y - py;
            float dz = pj.z - pz;
            // |minimum image| per axis: min(|d|, L-|d|); abs is a free modifier.
            float ax = fabsf(dx), ay = fabsf(dy), az = fabsf(dz);
            float wx = fminf(ax, Lx - ax);
            float wy = fminf(ay, Ly - ay);
            float wz = fminf(az, Lz - az);
            float r2 = fmaf(wx, wx, fmaf(wy, wy, wz * wz));
            if (r2 < thr2 && (j0 + t) != i) {
                // Signed MIC only where needed (rare).
                float sx = fmaf(-rintf(dx * iLx), Lx, dx);
                float sy = fmaf(-rintf(dy * iLy), Ly, dy);
                float sz = fmaf(-rintf(dz * iLz), Lz, dz);
                float4 tab = sh_tab[si8 + __float_as_int(pj.w)];
                float rinv = rsqrtf(r2);
                float r    = r2 * rinv;
                float f    = fmaf(-r, tab.x, 1.0f);   // 1 - r/sig
                if (f > 0.0f) {
                    float p = fast_pow(f, tab.y);        // f^(alpha-1)
                    e_acc = fmaf(tab.z * p, f, e_acc);   // eps/alpha * f^alpha
                    float c = tab.w * p * rinv;          // eps/(sig*r)*f^(a-1)
                    fxa = fmaf(-c, sx, fxa);
                    fya = fmaf(-c, sy, fya);
                    fza = fmaf(-c, sz, fza);
                }
            }
        }
    } else {
        // General triclinic path (not taken for this input, kept for correctness).
        const float det = m00 * (m11 * m22 - m12 * m21)
                        - m01 * (m10 * m22 - m12 * m20)
                        + m02 * (m10 * m21 - m11 * m20);
        const float rdet = 1.0f / det;
        const float i00 = (m11 * m22 - m12 * m21) * rdet;
        const float i01 = (m02 * m21 - m01 * m22) * rdet;
        const float i02 = (m01 * m12 - m02 * m11) * rdet;
        const float i10 = (m12 * m20 - m10 * m22) * rdet;
        const float i11 = (m00 * m22 - m02 * m20) * rdet;
        const float i12 = (m02 * m10 - m00 * m12) * rdet;
        const float i20 = (m10 * m21 - m11 * m20) * rdet;
        const float i21 = (m01 * m20 - m00 * m21) * rdet;
        const float i22 = (m00 * m11 - m01 * m10) * rdet;
#pragma unroll 2
        for (int t = 0; t < TJ; ++t) {
            float4 pj = sh_pos[t];
            float dx = pj.x - px, dy = pj.y - py, dz = pj.z - pz;
            float fx = dx * i00 + dy * i10 + dz * i20;
            float fy = dx * i01 + dy * i11 + dz * i21;
            float fz = dx * i02 + dy * i12 + dz * i22;
            fx -= rintf(fx); fy -= rintf(fy); fz -= rintf(fz);
            float ddx = fx * m00 + fy * m10 + fz * m20;
            float ddy = fx * m01 + fy * m11 + fz * m21;
            float ddz = fx * m02 + fy * m12 + fz * m22;
            float r2 = fmaf(ddx, ddx, fmaf(ddy, ddy, ddz * ddz));
            if (r2 < thr2 && (j0 + t) != i) {
                float4 tab = sh_tab[si8 + __float_as_int(pj.w)];
                float rinv = rsqrtf(r2);
                float r    = r2 * rinv;
                float f    = fmaf(-r, tab.x, 1.0f);
                if (f > 0.0f) {
                    float p = fast_pow(f, tab.y);
                    e_acc = fmaf(tab.z * p, f, e_acc);
                    float c = tab.w * p * rinv;
                    fxa = fmaf(-c, ddx, fxa);
                    fya = fmaf(-c, ddy, fya);
                    fza = fmaf(-c, ddz, fza);
                }
            }
        }
    }

    // Merge partial forces across j-chunk blocks (low-contention atomics).
    atomicAdd(&out[1 + 3 * i + 0], fxa);
    atomicAdd(&out[1 + 3 * i + 1], fya);
    atomicAdd(&out[1 + 3 * i + 2], fza);

    // Energy: wave shuffle reduce -> LDS across waves -> one atomic per block.
    for (int off = 32; off > 0; off >>= 1)
        e_acc += __shfl_down(e_acc, off, 64);
    if ((tid & 63) == 0) sh_red[tid >> 6] = e_acc;
    __syncthreads();
    if (tid == 0) {
        float tot = 0.0f;
        for (int w = 0; w < TI / 64; ++w) tot += sh_red[w];
        atomicAdd(&out[0], 0.5f * tot);  // ordered pairs counted twice
    }
}

extern "C" void kernel_launch(void* const* d_in, const int* in_sizes, int n_in,
                              void* d_out, int out_size, void* d_ws, size_t ws_size,
                              hipStream_t stream) {
    const float* pos  = (const float*)d_in[0];
    const float* cell = (const float*)d_in[1];
    const float* sigm = (const float*)d_in[2];
    const float* epsm = (const float*)d_in[3];
    const float* alpm = (const float*)d_in[4];
    const int*   spec = (const int*)d_in[5];
    float* out = (float*)d_out;
    const int n = in_sizes[5];  // species array length = N

    // We accumulate with atomics; harness poisons d_out with 0xAA each launch.
    (void)hipMemsetAsync(out, 0, (size_t)out_size * sizeof(float), stream);

    dim3 grid(n / TI, (n + TJ - 1) / TJ);
    soft_sphere_kernel<<<grid, TI, 0, stream>>>(pos, cell, sigm, epsm, alpm,
                                                spec, out, n);
}